// Round 11
// baseline (135.134 us; speedup 1.0000x reference)
//
#include <hip/hip_runtime.h>
#include <hip/hip_bf16.h>

// transformAttention fused MFMA kernel (round 11)
// Round-10 post-mortem: stall-dominated tail — FFN weights loaded cold after
// all LDS phases; 5 lgkmcnt fences (2 only due to tbuf-overlays-pbuf).
// Round 11 (math/layouts = r10): w1f+biases hoisted to top (drain free at B1),
// w2f issued after PV (hidden under tbuf+fence+FFN1), tbuf relocated to the
// dead v-slab (vv is in regs) -> 3 fences. FFN B rows 12..15 clamp to row 0.
// LDS map (36864 B, 4 blocks/CU):
//   [0,12288)      q slab [12s][8n][64d] bf16, swz ((s&7)^(n&7))<<4
//   [12288,24576)  k slab (same) | after B2: per-(w,ni) pbuf (8x3072)
//   [24576,36864)  v slab (same) | after PV reads: per-(w,ni) tbuf (8x1536)

typedef __attribute__((ext_vector_type(8))) short bf16x8;
typedef __attribute__((ext_vector_type(4))) float f32x4;

constexpr int Bb = 16, Ss = 12, Nn = 2048, Dd = 64;
constexpr float EXPK = 0.51011687f;   // (1/sqrt(8)) * log2(e)
constexpr int KOFS = 12288, VOFS = 24576, LDSZ = 36864;

#define MFMA16(A, B, C) __builtin_amdgcn_mfma_f32_16x16x32_bf16((A), (B), (C), 0, 0, 0)

__device__ __forceinline__ short f2bf(float f) {
    __hip_bfloat16 h = __float2bfloat16(f);
    short s; __builtin_memcpy(&s, &h, 2); return s;
}
__device__ __forceinline__ float bitf(unsigned u) {
    float f; __builtin_memcpy(&f, &u, 4); return f;
}
__device__ __forceinline__ float bf2f(unsigned short v) {
    return bitf(((unsigned)v) << 16);
}
__device__ __forceinline__ unsigned cvtpk(float lo, float hi) {
    unsigned r;
    asm("v_cvt_pk_bf16_f32 %0, %1, %2" : "=v"(r) : "v"(lo), "v"(hi));
    return r;
}
__device__ __forceinline__ void lds_fence() {
    asm volatile("s_waitcnt lgkmcnt(0)" ::: "memory");
    __builtin_amdgcn_sched_barrier(0);
}
// q/k/v slab byte offset (single source of truth for the swizzle)
__device__ __forceinline__ int qkOfs(int t, int s, int n, int d) {
    return t * KOFS + s * 1024 + n * 128 + ((2 * d) ^ (((s & 7) ^ (n & 7)) << 4));
}
// tbuf in v-slab: slot = w*2+ni, 12 rows x 128 B
__device__ __forceinline__ int vtOfs(int slot, int row, int d) {
    return VOFS + slot * 1536 + row * 128 + ((2 * d) ^ ((row & 7) << 4));
}

// prep: d_ws <- bf16 W^T for Wff, W1, W2: wt[m][r*64+c] = W[c][r]
__global__ void prep_w(const float* __restrict__ Wff, const float* __restrict__ W1,
                       const float* __restrict__ W2, unsigned short* __restrict__ wt) {
    int idx = blockIdx.x * 256 + threadIdx.x;
    if (idx >= 3 * 4096) return;
    int m = idx >> 12, rc = idx & 4095, r = rc >> 6, c = rc & 63;
    const float* W = (m == 0) ? Wff : (m == 1) ? W1 : W2;
    unsigned short u; short s = f2bf(W[c * 64 + r]);
    __builtin_memcpy(&u, &s, 2);
    wt[idx] = u;
}

__global__ __launch_bounds__(256, 4)
void ta_mfma9(const float* __restrict__ x,
              const float* __restrict__ steP,
              const float* __restrict__ steQ,
              const float* __restrict__ bff, const float* __restrict__ b1,
              const float* __restrict__ b2,
              const unsigned short* __restrict__ wt,
              float* __restrict__ out)
{
    alignas(16) __shared__ char smem[LDSZ];

    const int tid = threadIdx.x;
    const int w   = tid >> 6;      // 0..3
    const int l   = tid & 63;
    const int l15 = l & 15;
    const int l4  = l >> 4;
    const int b   = blockIdx.y;
    const int n0  = blockIdx.x * 8;

    // ---- hoisted loads: W_ff frags, W1 frags, all biases ----
    bf16x8 wf[4][2], w1f[4][2];
    float bfv[4], b1v[4], b2v[4];
    #pragma unroll
    for (int nt = 0; nt < 4; ++nt) {
        bfv[nt] = bff[nt * 16 + l15];
        b1v[nt] = b1[nt * 16 + l15];
        b2v[nt] = b2[nt * 16 + l15];
        #pragma unroll
        for (int kc = 0; kc < 2; ++kc) {
            wf[nt][kc]  = *(const bf16x8*)(wt +        (nt * 16 + l15) * 64 + kc * 32 + l4 * 8);
            w1f[nt][kc] = *(const bf16x8*)(wt + 4096 + (nt * 16 + l15) * 64 + kc * 32 + l4 * 8);
        }
    }

    // ---- phase 1: projections, 18 jobs = 3 tensors x 6 s-pairs, 4 waves ----
    const int sA = l15 >> 3, nA = l15 & 7;
    for (int job = w; job < 18; job += 4) {
        const int t = job / 6, s0 = (job % 6) * 2;
        const float* base = (t == 0) ? steQ : (t == 1) ? steP : x;
        const float* rp = base + ((size_t)(b * Ss + s0 + sA) * Nn + n0 + nA) * Dd + l4 * 8;

        bf16x8 a[2];
        #pragma unroll
        for (int kc = 0; kc < 2; ++kc) {
            float4 p0 = *(const float4*)(rp + kc * 32);
            float4 p1 = *(const float4*)(rp + kc * 32 + 4);
            union { unsigned u[4]; bf16x8 v; } cv;
            cv.u[0] = cvtpk(p0.x, p0.y); cv.u[1] = cvtpk(p0.z, p0.w);
            cv.u[2] = cvtpk(p1.x, p1.y); cv.u[3] = cvtpk(p1.z, p1.w);
            a[kc] = cv.v;
        }
        #pragma unroll
        for (int nt = 0; nt < 4; ++nt) {
            f32x4 acc = { bfv[nt], bfv[nt], bfv[nt], bfv[nt] };
            acc = MFMA16(a[0], wf[nt][0], acc);
            acc = MFMA16(a[1], wf[nt][1], acc);
            const int d = nt * 16 + l15;
            #pragma unroll
            for (int q = 0; q < 4; ++q) {
                const int r = l4 * 4 + q, s = s0 + (r >> 3), nn = r & 7;
                *(short*)(smem + qkOfs(t, s, nn, d)) = f2bf(acc[q]);
            }
        }
    }
    __syncthreads();   // B1: q,k,v ready (hoisted vmem also drained here)

    // ---- v rows into regs (lane = d), both ni ----
    float vv[2][12];
    #pragma unroll
    for (int ni = 0; ni < 2; ++ni)
        #pragma unroll
        for (int s = 0; s < 12; ++s)
            vv[ni][s] = bf2f(*(const unsigned short*)(smem + qkOfs(2, s, w * 2 + ni, l)));

    // ---- phase 2a: per-head QK^T (swapped) + softmax; both ni interleaved ----
    unsigned pw[2][8][2];
    #pragma unroll
    for (int h = 0; h < 8; ++h) {
        #pragma unroll
        for (int ni = 0; ni < 2; ++ni) {
            const int n = w * 2 + ni;
            union { unsigned u[4]; bf16x8 v; } akk;
            akk.v = *(const bf16x8*)(smem + qkOfs(1, l15, n, h * 8));
            bf16x8 aq = *(const bf16x8*)(smem + qkOfs(0, l15, n, h * 8));
            if (l4 != 0) { akk.u[0] = 0; akk.u[1] = 0; akk.u[2] = 0; akk.u[3] = 0; }
            f32x4 c = { 0.f, 0.f, 0.f, 0.f };
            c = MFMA16(akk.v, aq, c);     // S^T: row p = l4*4+reg, col q = l15
            float e[4];
            #pragma unroll
            for (int i = 0; i < 4; ++i) {
                float v = __builtin_amdgcn_exp2f(c[i] * EXPK);
                e[i] = (l4 == 3) ? 0.f : v;     // zero p >= 12 / garbage rows
            }
            float ssum = (e[0] + e[1]) + (e[2] + e[3]);
            ssum += __shfl_xor(ssum, 16);
            ssum += __shfl_xor(ssum, 32);
            float inv;
            asm("v_rcp_f32 %0, %1" : "=v"(inv) : "v"(ssum));
            pw[ni][h][0] = cvtpk(e[0] * inv, e[1] * inv);
            pw[ni][h][1] = cvtpk(e[2] * inv, e[3] * inv);
        }
    }
    __syncthreads();   // B2: q,k slabs dead -> per-wave pbuf region

    // ---- phase 2b: pbuf scatter + VALU PV, both ni ----
    #pragma unroll
    for (int ni = 0; ni < 2; ++ni) {
        const int pb = w * 6144 + ni * 3072;
        if (l15 < 12 && l4 < 3) {
            #pragma unroll
            for (int h = 0; h < 8; ++h) {
                uint2 u; u.x = pw[ni][h][0]; u.y = pw[ni][h][1];
                *(uint2*)(smem + pb + l15 * 256 + ((h * 32) ^ ((l15 & 7) << 5)) + l4 * 8) = u;
            }
        }
    }
    lds_fence();   // F1: pbuf visible before PV reads

    float oacc[2][12];
    const int hslot = (l >> 3) * 32;   // lane's head = d>>3
    #pragma unroll
    for (int q = 0; q < 12; ++q) {
        #pragma unroll
        for (int ni = 0; ni < 2; ++ni) {
            const char* qp = smem + w * 6144 + ni * 3072 + q * 256 + (hslot ^ ((q & 7) << 5));
            uint4 pa = *(const uint4*)(qp);
            uint2 pbx = *(const uint2*)(qp + 16);
            const unsigned wds[6] = { pa.x, pa.y, pa.z, pa.w, pbx.x, pbx.y };
            float a = 0.f;
            #pragma unroll
            for (int p2 = 0; p2 < 6; ++p2) {
                a = fmaf(bitf(wds[p2] << 16),         vv[ni][2 * p2],     a);
                a = fmaf(bitf(wds[p2] & 0xFFFF0000u), vv[ni][2 * p2 + 1], a);
            }
            oacc[ni][q] = a;
        }
    }

    // ---- issue W2 frag loads here: hidden under tbuf writes + F2 + FFN1 ----
    bf16x8 w2f[4][2];
    #pragma unroll
    for (int nt = 0; nt < 4; ++nt)
        #pragma unroll
        for (int kc = 0; kc < 2; ++kc)
            w2f[nt][kc] = *(const bf16x8*)(wt + 8192 + (nt * 16 + l15) * 64 + kc * 32 + l4 * 8);

    // ---- tbuf writes (v-slab; vv already in regs; no fence vs PV reads) ----
    #pragma unroll
    for (int ni = 0; ni < 2; ++ni)
        #pragma unroll
        for (int q = 0; q < 12; ++q)
            *(short*)(smem + vtOfs(w * 2 + ni, q, l)) = f2bf(oacc[ni][q]);
    lds_fence();   // F2: tbuf visible before FFN1 reads

    const int l15c = (l15 < 12) ? l15 : 0;   // clamp B rows 12..15 (C cols discarded)

    // ---- phase 3: FFN, wave-private, both ni ----
    #pragma unroll
    for (int ni = 0; ni < 2; ++ni) {
        const int slot = w * 2 + ni;
        bf16x8 a[2];
        #pragma unroll
        for (int kc = 0; kc < 2; ++kc)
            a[kc] = *(const bf16x8*)(smem + vtOfs(slot, l15c, kc * 32 + l4 * 8));
        #pragma unroll
        for (int nt = 0; nt < 4; ++nt) {
            f32x4 acc = { b1v[nt], b1v[nt], b1v[nt], b1v[nt] };
            acc = MFMA16(a[0], w1f[nt][0], acc);
            acc = MFMA16(a[1], w1f[nt][1], acc);
            #pragma unroll
            for (int reg = 0; reg < 4; ++reg) {
                const int rt = l4 * 4 + reg;
                if (rt < 12)
                    *(short*)(smem + vtOfs(slot, rt, nt * 16 + l15)) =
                        f2bf(fmaxf(acc[reg], 0.f));
            }
        }
    }
    lds_fence();   // F3: hid visible before FFN2 reads
    #pragma unroll
    for (int ni = 0; ni < 2; ++ni) {
        const int slot = w * 2 + ni;
        bf16x8 a[2];
        #pragma unroll
        for (int kc = 0; kc < 2; ++kc)
            a[kc] = *(const bf16x8*)(smem + vtOfs(slot, l15c, kc * 32 + l4 * 8));
        #pragma unroll
        for (int nt = 0; nt < 4; ++nt) {
            f32x4 acc = { b2v[nt], b2v[nt], b2v[nt], b2v[nt] };
            acc = MFMA16(a[0], w2f[nt][0], acc);
            acc = MFMA16(a[1], w2f[nt][1], acc);
            #pragma unroll
            for (int reg = 0; reg < 4; ++reg) {
                const int q = l4 * 4 + reg;
                if (q < 12)
                    out[((size_t)(b * Ss + q) * Nn + n0 + slot) * Dd + nt * 16 + l15] = acc[reg];
            }
        }
    }
}

extern "C" void kernel_launch(void* const* d_in, const int* in_sizes, int n_in,
                              void* d_out, int out_size, void* d_ws, size_t ws_size,
                              hipStream_t stream) {
    const float* x    = (const float*)d_in[0];
    const float* steP = (const float*)d_in[1];
    const float* steQ = (const float*)d_in[2];
    const float* Wff  = (const float*)d_in[3];
    const float* bff  = (const float*)d_in[4];
    const float* W1   = (const float*)d_in[5];
    const float* b1   = (const float*)d_in[6];
    const float* W2   = (const float*)d_in[7];
    const float* b2   = (const float*)d_in[8];
    float* out = (float*)d_out;
    unsigned short* wtp = (unsigned short*)d_ws;

    prep_w<<<48, 256, 0, stream>>>(Wff, W1, W2, wtp);
    dim3 grid(Nn / 8, Bb);
    ta_mfma9<<<grid, 256, 0, stream>>>(x, steP, steQ, bff, b1, b2, wtp, out);
}

// Round 12
// 135.103 us; speedup vs baseline: 1.0002x; 1.0002x over previous
//
#include <hip/hip_runtime.h>
#include <hip/hip_bf16.h>

// transformAttention fused MFMA kernel (round 12)
// Round-11 post-mortem: REGRESSION from register spills — WRITE +16MB, FETCH
// +8MB (scratch), VGPR pinned at 64. __launch_bounds__ 2nd arg is only a MIN
// waves/EU; allocator targeted 8 waves/EU (<=64 VGPR) and spilled the hoisted
// weight frags — but LDS (36864B -> 4 blocks/CU) caps us at 4 waves/EU anyway.
// Round 12 = r11 body + amdgpu_waves_per_eu(4,4): pins the target, VGPR
// budget 128, hoists stay in registers. No other changes.
// LDS map (36864 B, 4 blocks/CU):
//   [0,12288)      q slab [12s][8n][64d] bf16, swz ((s&7)^(n&7))<<4
//   [12288,24576)  k slab (same) | after B2: per-(w,ni) pbuf (8x3072)
//   [24576,36864)  v slab (same) | after PV reads: per-(w,ni) tbuf (8x1536)

typedef __attribute__((ext_vector_type(8))) short bf16x8;
typedef __attribute__((ext_vector_type(4))) float f32x4;

constexpr int Bb = 16, Ss = 12, Nn = 2048, Dd = 64;
constexpr float EXPK = 0.51011687f;   // (1/sqrt(8)) * log2(e)
constexpr int KOFS = 12288, VOFS = 24576, LDSZ = 36864;

#define MFMA16(A, B, C) __builtin_amdgcn_mfma_f32_16x16x32_bf16((A), (B), (C), 0, 0, 0)

__device__ __forceinline__ short f2bf(float f) {
    __hip_bfloat16 h = __float2bfloat16(f);
    short s; __builtin_memcpy(&s, &h, 2); return s;
}
__device__ __forceinline__ float bitf(unsigned u) {
    float f; __builtin_memcpy(&f, &u, 4); return f;
}
__device__ __forceinline__ float bf2f(unsigned short v) {
    return bitf(((unsigned)v) << 16);
}
__device__ __forceinline__ unsigned cvtpk(float lo, float hi) {
    unsigned r;
    asm("v_cvt_pk_bf16_f32 %0, %1, %2" : "=v"(r) : "v"(lo), "v"(hi));
    return r;
}
__device__ __forceinline__ void lds_fence() {
    asm volatile("s_waitcnt lgkmcnt(0)" ::: "memory");
    __builtin_amdgcn_sched_barrier(0);
}
// q/k/v slab byte offset (single source of truth for the swizzle)
__device__ __forceinline__ int qkOfs(int t, int s, int n, int d) {
    return t * KOFS + s * 1024 + n * 128 + ((2 * d) ^ (((s & 7) ^ (n & 7)) << 4));
}
// tbuf in v-slab: slot = w*2+ni, 12 rows x 128 B
__device__ __forceinline__ int vtOfs(int slot, int row, int d) {
    return VOFS + slot * 1536 + row * 128 + ((2 * d) ^ ((row & 7) << 4));
}

// prep: d_ws <- bf16 W^T for Wff, W1, W2: wt[m][r*64+c] = W[c][r]
__global__ void prep_w(const float* __restrict__ Wff, const float* __restrict__ W1,
                       const float* __restrict__ W2, unsigned short* __restrict__ wt) {
    int idx = blockIdx.x * 256 + threadIdx.x;
    if (idx >= 3 * 4096) return;
    int m = idx >> 12, rc = idx & 4095, r = rc >> 6, c = rc & 63;
    const float* W = (m == 0) ? Wff : (m == 1) ? W1 : W2;
    unsigned short u; short s = f2bf(W[c * 64 + r]);
    __builtin_memcpy(&u, &s, 2);
    wt[idx] = u;
}

__global__ __launch_bounds__(256)
__attribute__((amdgpu_waves_per_eu(4, 4)))
void ta_mfma10(const float* __restrict__ x,
               const float* __restrict__ steP,
               const float* __restrict__ steQ,
               const float* __restrict__ bff, const float* __restrict__ b1,
               const float* __restrict__ b2,
               const unsigned short* __restrict__ wt,
               float* __restrict__ out)
{
    alignas(16) __shared__ char smem[LDSZ];

    const int tid = threadIdx.x;
    const int w   = tid >> 6;      // 0..3
    const int l   = tid & 63;
    const int l15 = l & 15;
    const int l4  = l >> 4;
    const int b   = blockIdx.y;
    const int n0  = blockIdx.x * 8;

    // ---- hoisted loads: W_ff frags, W1 frags, all biases ----
    bf16x8 wf[4][2], w1f[4][2];
    float bfv[4], b1v[4], b2v[4];
    #pragma unroll
    for (int nt = 0; nt < 4; ++nt) {
        bfv[nt] = bff[nt * 16 + l15];
        b1v[nt] = b1[nt * 16 + l15];
        b2v[nt] = b2[nt * 16 + l15];
        #pragma unroll
        for (int kc = 0; kc < 2; ++kc) {
            wf[nt][kc]  = *(const bf16x8*)(wt +        (nt * 16 + l15) * 64 + kc * 32 + l4 * 8);
            w1f[nt][kc] = *(const bf16x8*)(wt + 4096 + (nt * 16 + l15) * 64 + kc * 32 + l4 * 8);
        }
    }

    // ---- phase 1: projections, 18 jobs = 3 tensors x 6 s-pairs, 4 waves ----
    const int sA = l15 >> 3, nA = l15 & 7;
    for (int job = w; job < 18; job += 4) {
        const int t = job / 6, s0 = (job % 6) * 2;
        const float* base = (t == 0) ? steQ : (t == 1) ? steP : x;
        const float* rp = base + ((size_t)(b * Ss + s0 + sA) * Nn + n0 + nA) * Dd + l4 * 8;

        bf16x8 a[2];
        #pragma unroll
        for (int kc = 0; kc < 2; ++kc) {
            float4 p0 = *(const float4*)(rp + kc * 32);
            float4 p1 = *(const float4*)(rp + kc * 32 + 4);
            union { unsigned u[4]; bf16x8 v; } cv;
            cv.u[0] = cvtpk(p0.x, p0.y); cv.u[1] = cvtpk(p0.z, p0.w);
            cv.u[2] = cvtpk(p1.x, p1.y); cv.u[3] = cvtpk(p1.z, p1.w);
            a[kc] = cv.v;
        }
        #pragma unroll
        for (int nt = 0; nt < 4; ++nt) {
            f32x4 acc = { bfv[nt], bfv[nt], bfv[nt], bfv[nt] };
            acc = MFMA16(a[0], wf[nt][0], acc);
            acc = MFMA16(a[1], wf[nt][1], acc);
            const int d = nt * 16 + l15;
            #pragma unroll
            for (int q = 0; q < 4; ++q) {
                const int r = l4 * 4 + q, s = s0 + (r >> 3), nn = r & 7;
                *(short*)(smem + qkOfs(t, s, nn, d)) = f2bf(acc[q]);
            }
        }
    }
    __syncthreads();   // B1: q,k,v ready (hoisted vmem also drained here)

    // ---- v rows into regs (lane = d), both ni ----
    float vv[2][12];
    #pragma unroll
    for (int ni = 0; ni < 2; ++ni)
        #pragma unroll
        for (int s = 0; s < 12; ++s)
            vv[ni][s] = bf2f(*(const unsigned short*)(smem + qkOfs(2, s, w * 2 + ni, l)));

    // ---- phase 2a: per-head QK^T (swapped) + softmax; both ni interleaved ----
    unsigned pw[2][8][2];
    #pragma unroll
    for (int h = 0; h < 8; ++h) {
        #pragma unroll
        for (int ni = 0; ni < 2; ++ni) {
            const int n = w * 2 + ni;
            union { unsigned u[4]; bf16x8 v; } akk;
            akk.v = *(const bf16x8*)(smem + qkOfs(1, l15, n, h * 8));
            bf16x8 aq = *(const bf16x8*)(smem + qkOfs(0, l15, n, h * 8));
            if (l4 != 0) { akk.u[0] = 0; akk.u[1] = 0; akk.u[2] = 0; akk.u[3] = 0; }
            f32x4 c = { 0.f, 0.f, 0.f, 0.f };
            c = MFMA16(akk.v, aq, c);     // S^T: row p = l4*4+reg, col q = l15
            float e[4];
            #pragma unroll
            for (int i = 0; i < 4; ++i) {
                float v = __builtin_amdgcn_exp2f(c[i] * EXPK);
                e[i] = (l4 == 3) ? 0.f : v;     // zero p >= 12 / garbage rows
            }
            float ssum = (e[0] + e[1]) + (e[2] + e[3]);
            ssum += __shfl_xor(ssum, 16);
            ssum += __shfl_xor(ssum, 32);
            float inv;
            asm("v_rcp_f32 %0, %1" : "=v"(inv) : "v"(ssum));
            pw[ni][h][0] = cvtpk(e[0] * inv, e[1] * inv);
            pw[ni][h][1] = cvtpk(e[2] * inv, e[3] * inv);
        }
    }
    __syncthreads();   // B2: q,k slabs dead -> per-wave pbuf region

    // ---- phase 2b: pbuf scatter + VALU PV, both ni ----
    #pragma unroll
    for (int ni = 0; ni < 2; ++ni) {
        const int pb = w * 6144 + ni * 3072;
        if (l15 < 12 && l4 < 3) {
            #pragma unroll
            for (int h = 0; h < 8; ++h) {
                uint2 u; u.x = pw[ni][h][0]; u.y = pw[ni][h][1];
                *(uint2*)(smem + pb + l15 * 256 + ((h * 32) ^ ((l15 & 7) << 5)) + l4 * 8) = u;
            }
        }
    }
    lds_fence();   // F1: pbuf visible before PV reads

    float oacc[2][12];
    const int hslot = (l >> 3) * 32;   // lane's head = d>>3
    #pragma unroll
    for (int q = 0; q < 12; ++q) {
        #pragma unroll
        for (int ni = 0; ni < 2; ++ni) {
            const char* qp = smem + w * 6144 + ni * 3072 + q * 256 + (hslot ^ ((q & 7) << 5));
            uint4 pa = *(const uint4*)(qp);
            uint2 pbx = *(const uint2*)(qp + 16);
            const unsigned wds[6] = { pa.x, pa.y, pa.z, pa.w, pbx.x, pbx.y };
            float a = 0.f;
            #pragma unroll
            for (int p2 = 0; p2 < 6; ++p2) {
                a = fmaf(bitf(wds[p2] << 16),         vv[ni][2 * p2],     a);
                a = fmaf(bitf(wds[p2] & 0xFFFF0000u), vv[ni][2 * p2 + 1], a);
            }
            oacc[ni][q] = a;
        }
    }

    // ---- issue W2 frag loads here: hidden under tbuf writes + F2 + FFN1 ----
    bf16x8 w2f[4][2];
    #pragma unroll
    for (int nt = 0; nt < 4; ++nt)
        #pragma unroll
        for (int kc = 0; kc < 2; ++kc)
            w2f[nt][kc] = *(const bf16x8*)(wt + 8192 + (nt * 16 + l15) * 64 + kc * 32 + l4 * 8);

    // ---- tbuf writes (v-slab; vv already in regs; no fence vs PV reads) ----
    #pragma unroll
    for (int ni = 0; ni < 2; ++ni)
        #pragma unroll
        for (int q = 0; q < 12; ++q)
            *(short*)(smem + vtOfs(w * 2 + ni, q, l)) = f2bf(oacc[ni][q]);
    lds_fence();   // F2: tbuf visible before FFN1 reads

    const int l15c = (l15 < 12) ? l15 : 0;   // clamp B rows 12..15 (C cols discarded)

    // ---- phase 3: FFN, wave-private, both ni ----
    #pragma unroll
    for (int ni = 0; ni < 2; ++ni) {
        const int slot = w * 2 + ni;
        bf16x8 a[2];
        #pragma unroll
        for (int kc = 0; kc < 2; ++kc)
            a[kc] = *(const bf16x8*)(smem + vtOfs(slot, l15c, kc * 32 + l4 * 8));
        #pragma unroll
        for (int nt = 0; nt < 4; ++nt) {
            f32x4 acc = { b1v[nt], b1v[nt], b1v[nt], b1v[nt] };
            acc = MFMA16(a[0], w1f[nt][0], acc);
            acc = MFMA16(a[1], w1f[nt][1], acc);
            #pragma unroll
            for (int reg = 0; reg < 4; ++reg) {
                const int rt = l4 * 4 + reg;
                if (rt < 12)
                    *(short*)(smem + vtOfs(slot, rt, nt * 16 + l15)) =
                        f2bf(fmaxf(acc[reg], 0.f));
            }
        }
    }
    lds_fence();   // F3: hid visible before FFN2 reads
    #pragma unroll
    for (int ni = 0; ni < 2; ++ni) {
        const int slot = w * 2 + ni;
        bf16x8 a[2];
        #pragma unroll
        for (int kc = 0; kc < 2; ++kc)
            a[kc] = *(const bf16x8*)(smem + vtOfs(slot, l15c, kc * 32 + l4 * 8));
        #pragma unroll
        for (int nt = 0; nt < 4; ++nt) {
            f32x4 acc = { b2v[nt], b2v[nt], b2v[nt], b2v[nt] };
            acc = MFMA16(a[0], w2f[nt][0], acc);
            acc = MFMA16(a[1], w2f[nt][1], acc);
            #pragma unroll
            for (int reg = 0; reg < 4; ++reg) {
                const int q = l4 * 4 + reg;
                if (q < 12)
                    out[((size_t)(b * Ss + q) * Nn + n0 + slot) * Dd + nt * 16 + l15] = acc[reg];
            }
        }
    }
}

extern "C" void kernel_launch(void* const* d_in, const int* in_sizes, int n_in,
                              void* d_out, int out_size, void* d_ws, size_t ws_size,
                              hipStream_t stream) {
    const float* x    = (const float*)d_in[0];
    const float* steP = (const float*)d_in[1];
    const float* steQ = (const float*)d_in[2];
    const float* Wff  = (const float*)d_in[3];
    const float* bff  = (const float*)d_in[4];
    const float* W1   = (const float*)d_in[5];
    const float* b1   = (const float*)d_in[6];
    const float* W2   = (const float*)d_in[7];
    const float* b2   = (const float*)d_in[8];
    float* out = (float*)d_out;
    unsigned short* wtp = (unsigned short*)d_ws;

    prep_w<<<48, 256, 0, stream>>>(Wff, W1, W2, wtp);
    dim3 grid(Nn / 8, Bb);
    ta_mfma10<<<grid, 256, 0, stream>>>(x, steP, steQ, bff, b1, b2, wtp, out);
}